// Round 15
// baseline (66.895 us; speedup 1.0000x reference)
//
#include <hip/hip_runtime.h>
#include <math.h>

typedef __attribute__((ext_vector_type(8))) short short8;
typedef __attribute__((ext_vector_type(4))) float f32x4;
using half8  = __attribute__((ext_vector_type(8))) _Float16;

constexpr int kN = 64;     // nodes per batch
constexpr int kF = 13;     // features
constexpr int kD = 128;    // hidden dim
constexpr int kSelf = 6;
constexpr float kTemp = 0.08838834764831845f;   // 1/sqrt(128)
constexpr float kLoScale = 4096.f;              // (kept in prep; unused by main kernel)

// ws layout (ushort element offsets) — identical to rounds 7-14.
constexpr int WS_QH  = 0;
constexpr int WS_QL  = 16384;
constexpr int WS_KH  = 32768;
constexpr int WS_KL  = 49152;
constexpr int WS_P3  = 65536;
constexpr int WS_P2  = 69632;
constexpr int WS_F32 = 73728;

__device__ __forceinline__ ushort f16h(float v) {
  _Float16 h = (_Float16)v;
  return __builtin_bit_cast(unsigned short, h);
}
__device__ __forceinline__ float f16f(ushort b) {
  return (float)__builtin_bit_cast(_Float16, b);
}
__device__ __forceinline__ half8 ld_h8(const ushort* p) {
  return __builtin_bit_cast(half8, *(const short8*)p);
}
__device__ __forceinline__ unsigned int pack_f16_rtz(float a, float b) {
  return __builtin_bit_cast(unsigned int, __builtin_amdgcn_cvt_pkrtz(a, b));
}
#define MFMA16(a, b, c) __builtin_amdgcn_mfma_f32_16x16x32_f16((a), (b), (c), 0, 0, 0)

__global__ __launch_bounds__(256) void prep_kernel(
    const float* __restrict__ q_w, const float* __restrict__ k_w,
    const float* __restrict__ p3w, const float* __restrict__ p2w,
    const float* __restrict__ v_w, const float* __restrict__ phi1_w,
    const float* __restrict__ phi1_b, const float* __restrict__ v_b,
    const float* __restrict__ final_w, const float* __restrict__ final_b,
    ushort* __restrict__ ws)
{
  const int i = blockIdx.x * 256 + threadIdx.x;
  if (i < 32768) {            // Q / K fragment planes (hi + lo; lo unused now)
    const int j = i & 16383;
    const bool isQ = i < 16384;
    const int c  = j >> 9;
    const int l  = (j >> 3) & 63;
    const int e  = j & 7;
    const int lc = l & 15, lg = l >> 4;
    const int drow = (c >> 2) * 16 + lc;
    const int ks   = c & 3;
    const float v = (isQ ? q_w : k_w)[drow * kD + ks * 32 + lg * 8 + e];
    const ushort h  = f16h(v);
    const ushort lo = f16h((v - f16f(h)) * kLoScale);
    if (isQ) { ws[WS_QH + j] = h; ws[WS_QL + j] = lo; }
    else     { ws[WS_KH + j] = h; ws[WS_KL + j] = lo; }
  } else if (i < 40960) {     // phi3 / phi2 hi-only fragment planes
    const int j = (i - 32768) & 4095;
    const bool is3 = i < 36864;
    const int nt = j >> 9;
    const int l  = (j >> 3) & 63;
    const int e  = j & 7;
    const int lc = l & 15, lg = l >> 4;
    const int dcol = nt * 16 + lc;
    const int k    = lg * 8 + e;
    const float v = (k < kF) ? (is3 ? p3w : p2w)[dcol * kF + k] : 0.f;
    ws[(is3 ? WS_P3 : WS_P2) + j] = f16h(v);
  } else if (i < 41088) {     // fvec[j] = sum_d final_w[d] * v_w[d][j]
    const int j = i - 40960;
    float acc = 0.f;
    for (int d2 = 0; d2 < kD; ++d2) acc = fmaf(final_w[d2], v_w[d2 * kD + j], acc);
    ((float*)(ws + WS_F32))[j] = acc;
  } else if (i < 41094) {     // gvec[j] = sum_d final_w[128+d] * phi1_w[d][j]
    const int j = i - 41088;
    float acc = 0.f;
    for (int d2 = 0; d2 < kD; ++d2) acc = fmaf(final_w[kD + d2], phi1_w[d2 * kSelf + j], acc);
    ((float*)(ws + WS_F32))[128 + j] = acc;
  } else if (i == 41094) {    // const
    float acc = final_b[0];
    for (int d2 = 0; d2 < kD; ++d2) acc = fmaf(final_w[d2], v_b[d2], acc);
    for (int d2 = 0; d2 < kD; ++d2) acc = fmaf(final_w[kD + d2], phi1_b[d2], acc);
    ((float*)(ws + WS_F32))[134] = acc;
  }
}

// One block (256 threads = 4 waves) per batch element. 2-barrier skeleton.
// C-phase weight fragments prefetched before phase B (L2 latency hidden
// under phase-B compute + barrier); phase C reads each h3 fragment once.
__global__ __launch_bounds__(256) void value_net_kernel(
    const float* __restrict__ state,
    const float* __restrict__ phi2_b, const float* __restrict__ phi3_b,
    const float* __restrict__ q_b,    const float* __restrict__ k_b,
    const ushort* __restrict__ wsc,
    float* __restrict__ out)
{
  const int b    = blockIdx.x;
  const int tid  = threadIdx.x;
  const int lane = tid & 63;
  const int wave = tid >> 6;
  const int lc   = lane & 15;   // fragment col / row-in-tile
  const int lg   = lane >> 4;   // fragment k-octet / row-group

  __shared__ __align__(16) ushort h3[kN * kD];    // f16 bits, XOR-swizzled
  __shared__ float spart[2][4][kN];               // per-dtl, per-wave score partials
  __shared__ float t_lds[kN];

  const float* fws = (const float*)(wsc + WS_F32);
  const int dbase = wave * 32;

  // ---- prefetch ALL phase-C weight fragments (16 x b128, ride out L2 latency
  //      under phase B + barrier) ----
  const int cb0 = (wave * 2 + 0) * 4;
  const int cb1 = (wave * 2 + 1) * 4;
  half8 wq0[4], wk0[4], wq1[4], wk1[4];
#pragma unroll
  for (int ks = 0; ks < 4; ++ks) {
    wq0[ks] = ld_h8(&wsc[WS_QH + (cb0 + ks) * 512 + lane * 8]);
    wk0[ks] = ld_h8(&wsc[WS_KH + (cb0 + ks) * 512 + lane * 8]);
    wq1[ks] = ld_h8(&wsc[WS_QH + (cb1 + ks) * 512 + lane * 8]);
    wk1[ks] = ld_h8(&wsc[WS_KH + (cb1 + ks) * 512 + lane * 8]);
  }

  // ---- B-fragment of state (f16) straight from global ----
  short8 a3s = {0, 0, 0, 0, 0, 0, 0, 0};
  if (lg < 2) {
    const float* rowp = state + (size_t)b * (kN * kF) + (wave * 16 + lc) * kF + lg * 8;
#pragma unroll
    for (int i = 0; i < 8; ++i) {
      const int k = lg * 8 + i;
      float x = 0.f;
      if (k < kF) x = rowp[i];
      a3s[i] = (short)f16h(x);
    }
  }
  const half8 a3 = __builtin_bit_cast(half8, a3s);

  // ---- phase B: swapped-operand phi3 + phi2-t ----
  // C = mfma(W_frag, state_frag): lane holds d = nt*16+lg*4+r, n = wave*16+lc.
  {
    const int n   = wave * 16 + lc;
    const int nsw = (n & 7) << 3;
    float tacc = 0.f;
#pragma unroll
    for (int nt = 0; nt < 8; ++nt) {
      half8 bh3 = ld_h8(&wsc[WS_P3 + nt * 512 + lane * 8]);
      half8 bh2 = ld_h8(&wsc[WS_P2 + nt * 512 + lane * 8]);
      f32x4 c3 = {0.f, 0.f, 0.f, 0.f};
      f32x4 c2 = {0.f, 0.f, 0.f, 0.f};
      c3 = MFMA16(bh3, a3, c3);
      c2 = MFMA16(bh2, a3, c2);
      const int d0 = nt * 16 + lg * 4;
      const float4 b3v = *(const float4*)&phi3_b[d0];
      const float4 b2v = *(const float4*)&phi2_b[d0];
      const float4 fv  = *(const float4*)&fws[d0];
      const float v0 = fmaxf(c3[0] + b3v.x, 0.f);
      const float v1 = fmaxf(c3[1] + b3v.y, 0.f);
      const float v2 = fmaxf(c3[2] + b3v.z, 0.f);
      const float v3 = fmaxf(c3[3] + b3v.w, 0.f);
      uint2 pw;
      pw.x = pack_f16_rtz(v0, v1);
      pw.y = pack_f16_rtz(v2, v3);
      *(uint2*)&h3[(n * kD + d0) ^ nsw] = pw;
      tacc = fmaf(fv.x, fmaxf(c2[0] + b2v.x, 0.f), tacc);
      tacc = fmaf(fv.y, fmaxf(c2[1] + b2v.y, 0.f), tacc);
      tacc = fmaf(fv.z, fmaxf(c2[2] + b2v.z, 0.f), tacc);
      tacc = fmaf(fv.w, fmaxf(c2[3] + b2v.w, 0.f), tacc);
    }
    tacc += __shfl_xor(tacc, 16, 64);
    tacc += __shfl_xor(tacc, 32, 64);
    if (lg == 0) t_lds[n] = tacc;
  }
  __syncthreads();  // h3 + t ready; prefetched weights long since landed

  // ---- phase C (fused Q+K, nt-outer): each h3 fragment read ONCE ----
  const float qb0 = q_b[dbase + lc];
  const float qb1 = q_b[dbase + 16 + lc];
  const float kb0 = k_b[dbase + lc];
  const float kb1 = k_b[dbase + 16 + lc];
  float qa0 = 0.f, qa1 = 0.f;
  float ka[2][4][4];   // K pre-activations, fully static indexing
#pragma unroll
  for (int nt = 0; nt < 4; ++nt) {
    const int rb  = (nt * 16 + lc) * kD;
    const int swz = ((nt * 16 + lc) & 7) << 3;
    half8 a0 = ld_h8(&h3[(rb + 0 * 32 + lg * 8) ^ swz]);
    half8 a1 = ld_h8(&h3[(rb + 1 * 32 + lg * 8) ^ swz]);
    half8 a2 = ld_h8(&h3[(rb + 2 * 32 + lg * 8) ^ swz]);
    half8 a3f = ld_h8(&h3[(rb + 3 * 32 + lg * 8) ^ swz]);
    f32x4 aQ0 = {0.f, 0.f, 0.f, 0.f}, aK0 = {0.f, 0.f, 0.f, 0.f};
    f32x4 aQ1 = {0.f, 0.f, 0.f, 0.f}, aK1 = {0.f, 0.f, 0.f, 0.f};
    aQ0 = MFMA16(a0, wq0[0], aQ0);  aK0 = MFMA16(a0, wk0[0], aK0);
    aQ1 = MFMA16(a0, wq1[0], aQ1);  aK1 = MFMA16(a0, wk1[0], aK1);
    aQ0 = MFMA16(a1, wq0[1], aQ0);  aK0 = MFMA16(a1, wk0[1], aK0);
    aQ1 = MFMA16(a1, wq1[1], aQ1);  aK1 = MFMA16(a1, wk1[1], aK1);
    aQ0 = MFMA16(a2, wq0[2], aQ0);  aK0 = MFMA16(a2, wk0[2], aK0);
    aQ1 = MFMA16(a2, wq1[2], aQ1);  aK1 = MFMA16(a2, wk1[2], aK1);
    aQ0 = MFMA16(a3f, wq0[3], aQ0); aK0 = MFMA16(a3f, wk0[3], aK0);
    aQ1 = MFMA16(a3f, wq1[3], aQ1); aK1 = MFMA16(a3f, wk1[3], aK1);
#pragma unroll
    for (int r = 0; r < 4; ++r) {
      qa0 += fmaxf(aQ0[r] + qb0, 0.f);
      qa1 += fmaxf(aQ1[r] + qb1, 0.f);
      ka[0][nt][r] = aK0[r];
      ka[1][nt][r] = aK1[r];
    }
  }
  // reduce qsum over the lg groups
  qa0 += __shfl_xor(qa0, 16, 64);
  qa0 += __shfl_xor(qa0, 32, 64);
  qa1 += __shfl_xor(qa1, 16, 64);
  qa1 += __shfl_xor(qa1, 32, 64);

  // score partials from saved K pre-activations
#pragma unroll
  for (int dtl = 0; dtl < 2; ++dtl) {
    const float qsv = (dtl == 0) ? qa0 : qa1;
    const float kb  = (dtl == 0) ? kb0 : kb1;
#pragma unroll
    for (int nt = 0; nt < 4; ++nt) {
      float pr[4];
#pragma unroll
      for (int r = 0; r < 4; ++r)
        pr[r] = qsv * fmaxf(ka[dtl][nt][r] + kb, 0.f);
#pragma unroll
      for (int r = 0; r < 4; ++r) {
        pr[r] += __shfl_xor(pr[r], 1, 64);
        pr[r] += __shfl_xor(pr[r], 2, 64);
        pr[r] += __shfl_xor(pr[r], 4, 64);
        pr[r] += __shfl_xor(pr[r], 8, 64);
      }
      if (lc == 0) {
#pragma unroll
        for (int r = 0; r < 4; ++r) spart[dtl][wave][nt * 16 + lg * 4 + r] = pr[r];
      }
    }
  }
  __syncthreads();  // spart ready (t_lds ready since previous barrier)

  // ---- phase D: softmax + output (wave 0 only) ----
  if (wave == 0) {
    const int m = lane;
    float sc = spart[0][0][m] + spart[0][1][m] + spart[0][2][m] + spart[0][3][m]
             + spart[1][0][m] + spart[1][1][m] + spart[1][2][m] + spart[1][3][m];
    sc = fmaxf(sc * kTemp, 0.f);
    float mx = sc;
#pragma unroll
    for (int off = 32; off > 0; off >>= 1) mx = fmaxf(mx, __shfl_xor(mx, off, 64));
    float e = __expf(sc - mx);
    float s = e;
#pragma unroll
    for (int off = 32; off > 0; off >>= 1) s += __shfl_xor(s, off, 64);
    float val = (e / s) * t_lds[m];
#pragma unroll
    for (int off = 32; off > 0; off >>= 1) val += __shfl_xor(val, off, 64);
    if (lane == 0) {
      float v = val + fws[134];
      const float* s0 = state + (size_t)b * (kN * kF);
#pragma unroll
      for (int j = 0; j < kSelf; ++j) v = fmaf(fws[128 + j], s0[j], v);
      out[b] = v;
    }
  }
}

extern "C" void kernel_launch(void* const* d_in, const int* in_sizes, int n_in,
                              void* d_out, int out_size, void* d_ws, size_t ws_size,
                              hipStream_t stream) {
  const float* state   = (const float*)d_in[0];
  const float* phi1_w  = (const float*)d_in[1];
  const float* phi1_b  = (const float*)d_in[2];
  const float* phi2_w  = (const float*)d_in[3];
  const float* phi2_b  = (const float*)d_in[4];
  const float* phi3_w  = (const float*)d_in[5];
  const float* phi3_b  = (const float*)d_in[6];
  const float* q_w     = (const float*)d_in[7];
  const float* q_b     = (const float*)d_in[8];
  const float* k_w     = (const float*)d_in[9];
  const float* k_b     = (const float*)d_in[10];
  const float* v_w     = (const float*)d_in[11];
  const float* v_b     = (const float*)d_in[12];
  const float* final_w = (const float*)d_in[13];
  const float* final_b = (const float*)d_in[14];
  float* out = (float*)d_out;
  ushort* ws = (ushort*)d_ws;

  prep_kernel<<<dim3(161), dim3(256), 0, stream>>>(
      q_w, k_w, phi3_w, phi2_w, v_w, phi1_w, phi1_b, v_b, final_w, final_b, ws);

  const int batches = in_sizes[0] / (kN * kF);  // 4096
  value_net_kernel<<<dim3(batches), dim3(256), 0, stream>>>(
      state, phi2_b, phi3_b, q_b, k_b, ws, out);
}

// Round 16
// 51.338 us; speedup vs baseline: 1.3030x; 1.3030x over previous
//
#include <hip/hip_runtime.h>
#include <math.h>

typedef __attribute__((ext_vector_type(8))) short short8;
typedef __attribute__((ext_vector_type(4))) float f32x4;
using half8  = __attribute__((ext_vector_type(8))) _Float16;

constexpr int kN = 64;     // nodes per batch
constexpr int kF = 13;     // features
constexpr int kD = 128;    // hidden dim
constexpr int kSelf = 6;
constexpr float kTemp = 0.08838834764831845f;   // 1/sqrt(128)
constexpr float kLoScale = 4096.f;              // (kept in prep; unused by main kernel)

// ws layout (ushort element offsets) — identical to rounds 7-15.
constexpr int WS_QH  = 0;
constexpr int WS_QL  = 16384;
constexpr int WS_KH  = 32768;
constexpr int WS_KL  = 49152;
constexpr int WS_P3  = 65536;
constexpr int WS_P2  = 69632;
constexpr int WS_F32 = 73728;

__device__ __forceinline__ ushort f16h(float v) {
  _Float16 h = (_Float16)v;
  return __builtin_bit_cast(unsigned short, h);
}
__device__ __forceinline__ float f16f(ushort b) {
  return (float)__builtin_bit_cast(_Float16, b);
}
__device__ __forceinline__ half8 ld_h8(const ushort* p) {
  return __builtin_bit_cast(half8, *(const short8*)p);
}
__device__ __forceinline__ unsigned int pack_f16_rtz(float a, float b) {
  return __builtin_bit_cast(unsigned int, __builtin_amdgcn_cvt_pkrtz(a, b));
}
// VALU-pipe cross-lane add within a 16-lane row (DPP), replacing ds_bpermute
// shuffles on the congested per-CU LDS pipe.
template <int CTRL>
__device__ __forceinline__ float dpp_add(float x) {
  int v = __builtin_amdgcn_update_dpp(0, __builtin_bit_cast(int, x),
                                      CTRL, 0xF, 0xF, true);
  return x + __builtin_bit_cast(float, v);
}
// Full row-16 sum (all lanes end with the row sum):
__device__ __forceinline__ float row16_sum(float x) {
  x = dpp_add<0xB1>(x);    // quad_perm [1,0,3,2]  : xor 1
  x = dpp_add<0x4E>(x);    // quad_perm [2,3,0,1]  : xor 2
  x = dpp_add<0x124>(x);   // row_ror:4
  x = dpp_add<0x128>(x);   // row_ror:8
  return x;
}
#define MFMA16(a, b, c) __builtin_amdgcn_mfma_f32_16x16x32_f16((a), (b), (c), 0, 0, 0)

__global__ __launch_bounds__(256) void prep_kernel(
    const float* __restrict__ q_w, const float* __restrict__ k_w,
    const float* __restrict__ p3w, const float* __restrict__ p2w,
    const float* __restrict__ v_w, const float* __restrict__ phi1_w,
    const float* __restrict__ phi1_b, const float* __restrict__ v_b,
    const float* __restrict__ final_w, const float* __restrict__ final_b,
    ushort* __restrict__ ws)
{
  const int i = blockIdx.x * 256 + threadIdx.x;
  if (i < 32768) {            // Q / K fragment planes (hi + lo; lo unused now)
    const int j = i & 16383;
    const bool isQ = i < 16384;
    const int c  = j >> 9;
    const int l  = (j >> 3) & 63;
    const int e  = j & 7;
    const int lc = l & 15, lg = l >> 4;
    const int drow = (c >> 2) * 16 + lc;
    const int ks   = c & 3;
    const float v = (isQ ? q_w : k_w)[drow * kD + ks * 32 + lg * 8 + e];
    const ushort h  = f16h(v);
    const ushort lo = f16h((v - f16f(h)) * kLoScale);
    if (isQ) { ws[WS_QH + j] = h; ws[WS_QL + j] = lo; }
    else     { ws[WS_KH + j] = h; ws[WS_KL + j] = lo; }
  } else if (i < 40960) {     // phi3 / phi2 hi-only fragment planes
    const int j = (i - 32768) & 4095;
    const bool is3 = i < 36864;
    const int nt = j >> 9;
    const int l  = (j >> 3) & 63;
    const int e  = j & 7;
    const int lc = l & 15, lg = l >> 4;
    const int dcol = nt * 16 + lc;
    const int k    = lg * 8 + e;
    const float v = (k < kF) ? (is3 ? p3w : p2w)[dcol * kF + k] : 0.f;
    ws[(is3 ? WS_P3 : WS_P2) + j] = f16h(v);
  } else if (i < 41088) {     // fvec[j] = sum_d final_w[d] * v_w[d][j]
    const int j = i - 40960;
    float acc = 0.f;
    for (int d2 = 0; d2 < kD; ++d2) acc = fmaf(final_w[d2], v_w[d2 * kD + j], acc);
    ((float*)(ws + WS_F32))[j] = acc;
  } else if (i < 41094) {     // gvec[j] = sum_d final_w[128+d] * phi1_w[d][j]
    const int j = i - 41088;
    float acc = 0.f;
    for (int d2 = 0; d2 < kD; ++d2) acc = fmaf(final_w[kD + d2], phi1_w[d2 * kSelf + j], acc);
    ((float*)(ws + WS_F32))[128 + j] = acc;
  } else if (i == 41094) {    // const
    float acc = final_b[0];
    for (int d2 = 0; d2 < kD; ++d2) acc = fmaf(final_w[d2], v_b[d2], acc);
    for (int d2 = 0; d2 < kD; ++d2) acc = fmaf(final_w[kD + d2], phi1_b[d2], acc);
    ((float*)(ws + WS_F32))[134] = acc;
  }
}

// One block (256 threads = 4 waves) per batch element. 2-barrier skeleton.
// R14 structure (champion); phase-C score reduction moved from ds_bpermute
// (LDS pipe) to DPP adds (VALU pipe).
__global__ __launch_bounds__(256) void value_net_kernel(
    const float* __restrict__ state,
    const float* __restrict__ phi2_b, const float* __restrict__ phi3_b,
    const float* __restrict__ q_b,    const float* __restrict__ k_b,
    const ushort* __restrict__ wsc,
    float* __restrict__ out)
{
  const int b    = blockIdx.x;
  const int tid  = threadIdx.x;
  const int lane = tid & 63;
  const int wave = tid >> 6;
  const int lc   = lane & 15;   // fragment col / row-in-tile
  const int lg   = lane >> 4;   // fragment k-octet / row-group

  __shared__ __align__(16) ushort h3[kN * kD];    // f16 bits, XOR-swizzled
  __shared__ float spart[2][4][kN];               // per-dtl, per-wave score partials
  __shared__ float t_lds[kN];

  const float* fws = (const float*)(wsc + WS_F32);

  // ---- B-fragment of state (f16) straight from global ----
  short8 a3s = {0, 0, 0, 0, 0, 0, 0, 0};
  if (lg < 2) {
    const float* rowp = state + (size_t)b * (kN * kF) + (wave * 16 + lc) * kF + lg * 8;
#pragma unroll
    for (int i = 0; i < 8; ++i) {
      const int k = lg * 8 + i;
      float x = 0.f;
      if (k < kF) x = rowp[i];
      a3s[i] = (short)f16h(x);
    }
  }
  const half8 a3 = __builtin_bit_cast(half8, a3s);

  // ---- phase B: swapped-operand phi3 + phi2-t ----
  // C = mfma(W_frag, state_frag): lane holds d = nt*16+lg*4+r, n = wave*16+lc.
  {
    const int n   = wave * 16 + lc;
    const int nsw = (n & 7) << 3;
    float tacc = 0.f;
#pragma unroll
    for (int nt = 0; nt < 8; ++nt) {
      half8 bh3 = ld_h8(&wsc[WS_P3 + nt * 512 + lane * 8]);
      half8 bh2 = ld_h8(&wsc[WS_P2 + nt * 512 + lane * 8]);
      f32x4 c3 = {0.f, 0.f, 0.f, 0.f};
      f32x4 c2 = {0.f, 0.f, 0.f, 0.f};
      c3 = MFMA16(bh3, a3, c3);
      c2 = MFMA16(bh2, a3, c2);
      const int d0 = nt * 16 + lg * 4;
      const float4 b3v = *(const float4*)&phi3_b[d0];
      const float4 b2v = *(const float4*)&phi2_b[d0];
      const float4 fv  = *(const float4*)&fws[d0];
      const float v0 = fmaxf(c3[0] + b3v.x, 0.f);
      const float v1 = fmaxf(c3[1] + b3v.y, 0.f);
      const float v2 = fmaxf(c3[2] + b3v.z, 0.f);
      const float v3 = fmaxf(c3[3] + b3v.w, 0.f);
      uint2 pw;
      pw.x = pack_f16_rtz(v0, v1);
      pw.y = pack_f16_rtz(v2, v3);
      *(uint2*)&h3[(n * kD + d0) ^ nsw] = pw;
      tacc = fmaf(fv.x, fmaxf(c2[0] + b2v.x, 0.f), tacc);
      tacc = fmaf(fv.y, fmaxf(c2[1] + b2v.y, 0.f), tacc);
      tacc = fmaf(fv.z, fmaxf(c2[2] + b2v.z, 0.f), tacc);
      tacc = fmaf(fv.w, fmaxf(c2[3] + b2v.w, 0.f), tacc);
    }
    tacc += __shfl_xor(tacc, 16, 64);
    tacc += __shfl_xor(tacc, 32, 64);
    if (lg == 0) t_lds[n] = tacc;
  }
  __syncthreads();  // h3 + t ready

  const int dbase = wave * 32;

  // ---- phase C (fused Q+K), dtl-outer (R14 structure) ----
#pragma unroll
  for (int dtl = 0; dtl < 2; ++dtl) {
    const float qb = q_b[dbase + dtl * 16 + lc];
    const float kb = k_b[dbase + dtl * 16 + lc];
    const int cb = (wave * 2 + dtl) * 4;
    half8 bq0 = ld_h8(&wsc[WS_QH + (cb + 0) * 512 + lane * 8]);
    half8 bq1 = ld_h8(&wsc[WS_QH + (cb + 1) * 512 + lane * 8]);
    half8 bq2 = ld_h8(&wsc[WS_QH + (cb + 2) * 512 + lane * 8]);
    half8 bq3 = ld_h8(&wsc[WS_QH + (cb + 3) * 512 + lane * 8]);
    half8 bk0 = ld_h8(&wsc[WS_KH + (cb + 0) * 512 + lane * 8]);
    half8 bk1 = ld_h8(&wsc[WS_KH + (cb + 1) * 512 + lane * 8]);
    half8 bk2 = ld_h8(&wsc[WS_KH + (cb + 2) * 512 + lane * 8]);
    half8 bk3 = ld_h8(&wsc[WS_KH + (cb + 3) * 512 + lane * 8]);

    float qa = 0.f;
    float ka[4][4];   // K pre-activations, fully unrolled -> registers
#pragma unroll
    for (int nt = 0; nt < 4; ++nt) {
      const int rb  = (nt * 16 + lc) * kD;
      const int swz = ((nt * 16 + lc) & 7) << 3;
      half8 a0 = ld_h8(&h3[(rb + 0 * 32 + lg * 8) ^ swz]);
      half8 a1 = ld_h8(&h3[(rb + 1 * 32 + lg * 8) ^ swz]);
      half8 a2 = ld_h8(&h3[(rb + 2 * 32 + lg * 8) ^ swz]);
      half8 a3f = ld_h8(&h3[(rb + 3 * 32 + lg * 8) ^ swz]);
      f32x4 aQ = {0.f, 0.f, 0.f, 0.f};
      f32x4 aK = {0.f, 0.f, 0.f, 0.f};
      aQ = MFMA16(a0, bq0, aQ);  aK = MFMA16(a0, bk0, aK);
      aQ = MFMA16(a1, bq1, aQ);  aK = MFMA16(a1, bk1, aK);
      aQ = MFMA16(a2, bq2, aQ);  aK = MFMA16(a2, bk2, aK);
      aQ = MFMA16(a3f, bq3, aQ); aK = MFMA16(a3f, bk3, aK);
#pragma unroll
      for (int r = 0; r < 4; ++r) {
        qa += fmaxf(aQ[r] + qb, 0.f);
        ka[nt][r] = aK[r];
      }
    }
    // reduce qsum over the lg groups (cross-row: keep shfl, only 4 ops)
    qa += __shfl_xor(qa, 16, 64);
    qa += __shfl_xor(qa, 32, 64);
    const float qsv = qa;

    // score partials from saved K pre-activations — DPP row-16 reduction (VALU)
#pragma unroll
    for (int nt = 0; nt < 4; ++nt) {
      float pr[4];
#pragma unroll
      for (int r = 0; r < 4; ++r) {
        pr[r] = qsv * fmaxf(ka[nt][r] + kb, 0.f);
        pr[r] = row16_sum(pr[r]);
      }
      if (lc == 0) {
#pragma unroll
        for (int r = 0; r < 4; ++r) spart[dtl][wave][nt * 16 + lg * 4 + r] = pr[r];
      }
    }
  }
  __syncthreads();  // spart ready (t_lds ready since previous barrier)

  // ---- phase D: softmax + output (wave 0 only) ----
  if (wave == 0) {
    const int m = lane;
    float sc = spart[0][0][m] + spart[0][1][m] + spart[0][2][m] + spart[0][3][m]
             + spart[1][0][m] + spart[1][1][m] + spart[1][2][m] + spart[1][3][m];
    sc = fmaxf(sc * kTemp, 0.f);
    float mx = sc;
#pragma unroll
    for (int off = 32; off > 0; off >>= 1) mx = fmaxf(mx, __shfl_xor(mx, off, 64));
    float e = __expf(sc - mx);
    float s = e;
#pragma unroll
    for (int off = 32; off > 0; off >>= 1) s += __shfl_xor(s, off, 64);
    float val = (e / s) * t_lds[m];
#pragma unroll
    for (int off = 32; off > 0; off >>= 1) val += __shfl_xor(val, off, 64);
    if (lane == 0) {
      float v = val + fws[134];
      const float* s0 = state + (size_t)b * (kN * kF);
#pragma unroll
      for (int j = 0; j < kSelf; ++j) v = fmaf(fws[128 + j], s0[j], v);
      out[b] = v;
    }
  }
}

extern "C" void kernel_launch(void* const* d_in, const int* in_sizes, int n_in,
                              void* d_out, int out_size, void* d_ws, size_t ws_size,
                              hipStream_t stream) {
  const float* state   = (const float*)d_in[0];
  const float* phi1_w  = (const float*)d_in[1];
  const float* phi1_b  = (const float*)d_in[2];
  const float* phi2_w  = (const float*)d_in[3];
  const float* phi2_b  = (const float*)d_in[4];
  const float* phi3_w  = (const float*)d_in[5];
  const float* phi3_b  = (const float*)d_in[6];
  const float* q_w     = (const float*)d_in[7];
  const float* q_b     = (const float*)d_in[8];
  const float* k_w     = (const float*)d_in[9];
  const float* k_b     = (const float*)d_in[10];
  const float* v_w     = (const float*)d_in[11];
  const float* v_b     = (const float*)d_in[12];
  const float* final_w = (const float*)d_in[13];
  const float* final_b = (const float*)d_in[14];
  float* out = (float*)d_out;
  ushort* ws = (ushort*)d_ws;

  prep_kernel<<<dim3(161), dim3(256), 0, stream>>>(
      q_w, k_w, phi3_w, phi2_w, v_w, phi1_w, phi1_b, v_b, final_w, final_b, ws);

  const int batches = in_sizes[0] / (kN * kF);  // 4096
  value_net_kernel<<<dim3(batches), dim3(256), 0, stream>>>(
      state, phi2_b, phi3_b, q_b, k_b, ws, out);
}

// Round 17
// 44.027 us; speedup vs baseline: 1.5194x; 1.1661x over previous
//
#include <hip/hip_runtime.h>
#include <math.h>

typedef __attribute__((ext_vector_type(8))) short short8;
typedef __attribute__((ext_vector_type(4))) float f32x4;
using half8  = __attribute__((ext_vector_type(8))) _Float16;

constexpr int kN = 64;     // nodes per batch
constexpr int kF = 13;     // features
constexpr int kD = 128;    // hidden dim
constexpr int kSelf = 6;
constexpr float kTemp = 0.08838834764831845f;   // 1/sqrt(128)
constexpr float kLoScale = 4096.f;              // (kept in prep; unused by main kernel)

// ws layout (ushort element offsets) — identical to rounds 7-16.
// NOTE: phi planes' k=13 row now holds the BIAS (state pad column 13 = 1.0).
constexpr int WS_QH  = 0;
constexpr int WS_QL  = 16384;
constexpr int WS_KH  = 32768;
constexpr int WS_KL  = 49152;
constexpr int WS_P3  = 65536;
constexpr int WS_P2  = 69632;
constexpr int WS_F32 = 73728;

__device__ __forceinline__ ushort f16h(float v) {
  _Float16 h = (_Float16)v;
  return __builtin_bit_cast(unsigned short, h);
}
__device__ __forceinline__ float f16f(ushort b) {
  return (float)__builtin_bit_cast(_Float16, b);
}
__device__ __forceinline__ half8 ld_h8(const ushort* p) {
  return __builtin_bit_cast(half8, *(const short8*)p);
}
__device__ __forceinline__ unsigned int pack_f16_rtz(float a, float b) {
  return __builtin_bit_cast(unsigned int, __builtin_amdgcn_cvt_pkrtz(a, b));
}
#define MFMA16(a, b, c) __builtin_amdgcn_mfma_f32_16x16x32_f16((a), (b), (c), 0, 0, 0)

__global__ __launch_bounds__(256) void prep_kernel(
    const float* __restrict__ q_w, const float* __restrict__ k_w,
    const float* __restrict__ p3w, const float* __restrict__ p2w,
    const float* __restrict__ p3b, const float* __restrict__ p2b,
    const float* __restrict__ v_w, const float* __restrict__ phi1_w,
    const float* __restrict__ phi1_b, const float* __restrict__ v_b,
    const float* __restrict__ final_w, const float* __restrict__ final_b,
    ushort* __restrict__ ws)
{
  const int i = blockIdx.x * 256 + threadIdx.x;
  if (i < 32768) {            // Q / K fragment planes (hi + lo; lo unused now)
    const int j = i & 16383;
    const bool isQ = i < 16384;
    const int c  = j >> 9;
    const int l  = (j >> 3) & 63;
    const int e  = j & 7;
    const int lc = l & 15, lg = l >> 4;
    const int drow = (c >> 2) * 16 + lc;
    const int ks   = c & 3;
    const float v = (isQ ? q_w : k_w)[drow * kD + ks * 32 + lg * 8 + e];
    const ushort h  = f16h(v);
    const ushort lo = f16h((v - f16f(h)) * kLoScale);
    if (isQ) { ws[WS_QH + j] = h; ws[WS_QL + j] = lo; }
    else     { ws[WS_KH + j] = h; ws[WS_KL + j] = lo; }
  } else if (i < 40960) {     // phi3 / phi2 fragment planes; row 13 = bias
    const int j = (i - 32768) & 4095;
    const bool is3 = i < 36864;
    const int nt = j >> 9;
    const int l  = (j >> 3) & 63;
    const int e  = j & 7;
    const int lc = l & 15, lg = l >> 4;
    const int dcol = nt * 16 + lc;
    const int k    = lg * 8 + e;
    float v;
    if (k < kF)       v = (is3 ? p3w : p2w)[dcol * kF + k];
    else if (k == kF) v = (is3 ? p3b : p2b)[dcol];   // bias slot (state[13]=1)
    else              v = 0.f;
    ws[(is3 ? WS_P3 : WS_P2) + j] = f16h(v);
  } else if (i < 41088) {     // fvec[j] = sum_d final_w[d] * v_w[d][j]
    const int j = i - 40960;
    float acc = 0.f;
    for (int d2 = 0; d2 < kD; ++d2) acc = fmaf(final_w[d2], v_w[d2 * kD + j], acc);
    ((float*)(ws + WS_F32))[j] = acc;
  } else if (i < 41094) {     // gvec[j] = sum_d final_w[128+d] * phi1_w[d][j]
    const int j = i - 41088;
    float acc = 0.f;
    for (int d2 = 0; d2 < kD; ++d2) acc = fmaf(final_w[kD + d2], phi1_w[d2 * kSelf + j], acc);
    ((float*)(ws + WS_F32))[128 + j] = acc;
  } else if (i == 41094) {    // const
    float acc = final_b[0];
    for (int d2 = 0; d2 < kD; ++d2) acc = fmaf(final_w[d2], v_b[d2], acc);
    for (int d2 = 0; d2 < kD; ++d2) acc = fmaf(final_w[kD + d2], phi1_b[d2], acc);
    ((float*)(ws + WS_F32))[134] = acc;
  }
}

// One block (256 threads = 4 waves) per batch element. 2-barrier skeleton.
// Swapped-operand K pass (C[d][node]): score contraction is in-lane fmaf +
// 2 shfls instead of 16-lane DPP trees. Bias folded into phase-B MFMA.
__global__ __launch_bounds__(256) void value_net_kernel(
    const float* __restrict__ state,
    const float* __restrict__ q_b,    const float* __restrict__ k_b,
    const ushort* __restrict__ wsc,
    float* __restrict__ out)
{
  const int b    = blockIdx.x;
  const int tid  = threadIdx.x;
  const int lane = tid & 63;
  const int wave = tid >> 6;
  const int lc   = lane & 15;   // fragment col / row-in-tile
  const int lg   = lane >> 4;   // fragment k-octet / row-group

  __shared__ __align__(16) ushort h3[kN * kD];    // f16 bits, XOR-swizzled
  __shared__ float spart[2][4][kN];               // per-dtl, per-wave score partials
  __shared__ float t_lds[kN];

  const float* fws = (const float*)(wsc + WS_F32);

  // ---- B-fragment of state (f16); pad col 13 = 1.0 carries the bias ----
  short8 a3s = {0, 0, 0, 0, 0, 0, 0, 0};
  if (lg < 2) {
    const float* rowp = state + (size_t)b * (kN * kF) + (wave * 16 + lc) * kF + lg * 8;
#pragma unroll
    for (int i = 0; i < 8; ++i) {
      const int k = lg * 8 + i;
      float x;
      if (k < kF)       x = rowp[i];
      else if (k == kF) x = 1.0f;
      else              x = 0.f;
      a3s[i] = (short)f16h(x);
    }
  }
  const half8 a3 = __builtin_bit_cast(half8, a3s);

  // ---- phase B: swapped-operand phi3 + phi2-t (bias inside MFMA) ----
  {
    const int n   = wave * 16 + lc;
    const int nsw = (n & 7) << 3;
    float tacc = 0.f;
#pragma unroll
    for (int nt = 0; nt < 8; ++nt) {
      half8 bh3 = ld_h8(&wsc[WS_P3 + nt * 512 + lane * 8]);
      half8 bh2 = ld_h8(&wsc[WS_P2 + nt * 512 + lane * 8]);
      f32x4 c3 = {0.f, 0.f, 0.f, 0.f};
      f32x4 c2 = {0.f, 0.f, 0.f, 0.f};
      c3 = MFMA16(bh3, a3, c3);
      c2 = MFMA16(bh2, a3, c2);
      const int d0 = nt * 16 + lg * 4;
      const float4 fv = *(const float4*)&fws[d0];
      const float v0 = fmaxf(c3[0], 0.f);
      const float v1 = fmaxf(c3[1], 0.f);
      const float v2 = fmaxf(c3[2], 0.f);
      const float v3 = fmaxf(c3[3], 0.f);
      uint2 pw;
      pw.x = pack_f16_rtz(v0, v1);
      pw.y = pack_f16_rtz(v2, v3);
      *(uint2*)&h3[(n * kD + d0) ^ nsw] = pw;
      tacc = fmaf(fv.x, fmaxf(c2[0], 0.f), tacc);
      tacc = fmaf(fv.y, fmaxf(c2[1], 0.f), tacc);
      tacc = fmaf(fv.z, fmaxf(c2[2], 0.f), tacc);
      tacc = fmaf(fv.w, fmaxf(c2[3], 0.f), tacc);
    }
    tacc += __shfl_xor(tacc, 16, 64);
    tacc += __shfl_xor(tacc, 32, 64);
    if (lg == 0) t_lds[n] = tacc;
  }
  __syncthreads();  // h3 + t ready

  const int dbase = wave * 32;

  // ---- phase C (fused Q + swapped-K), dtl-outer ----
#pragma unroll
  for (int dtl = 0; dtl < 2; ++dtl) {
    const float qb = q_b[dbase + dtl * 16 + lc];
    const float4 kb4 = *(const float4*)&k_b[dbase + dtl * 16 + lg * 4];
    const int cb = (wave * 2 + dtl) * 4;
    half8 bq0 = ld_h8(&wsc[WS_QH + (cb + 0) * 512 + lane * 8]);
    half8 bq1 = ld_h8(&wsc[WS_QH + (cb + 1) * 512 + lane * 8]);
    half8 bq2 = ld_h8(&wsc[WS_QH + (cb + 2) * 512 + lane * 8]);
    half8 bq3 = ld_h8(&wsc[WS_QH + (cb + 3) * 512 + lane * 8]);
    half8 bk0 = ld_h8(&wsc[WS_KH + (cb + 0) * 512 + lane * 8]);
    half8 bk1 = ld_h8(&wsc[WS_KH + (cb + 1) * 512 + lane * 8]);
    half8 bk2 = ld_h8(&wsc[WS_KH + (cb + 2) * 512 + lane * 8]);
    half8 bk3 = ld_h8(&wsc[WS_KH + (cb + 3) * 512 + lane * 8]);

    float qa = 0.f;
    f32x4 kacc[4];   // swapped-K outputs: kacc[nt][r] = K[d=dtl*16+lg*4+r][node=nt*16+lc]
#pragma unroll
    for (int nt = 0; nt < 4; ++nt) {
      const int rb  = (nt * 16 + lc) * kD;
      const int swz = ((nt * 16 + lc) & 7) << 3;
      half8 a0 = ld_h8(&h3[(rb + 0 * 32 + lg * 8) ^ swz]);
      half8 a1 = ld_h8(&h3[(rb + 1 * 32 + lg * 8) ^ swz]);
      half8 a2 = ld_h8(&h3[(rb + 2 * 32 + lg * 8) ^ swz]);
      half8 a3f = ld_h8(&h3[(rb + 3 * 32 + lg * 8) ^ swz]);
      f32x4 aQ = {0.f, 0.f, 0.f, 0.f};
      f32x4 aK = {0.f, 0.f, 0.f, 0.f};
      aQ = MFMA16(a0, bq0, aQ);  aK = MFMA16(bk0, a0, aK);
      aQ = MFMA16(a1, bq1, aQ);  aK = MFMA16(bk1, a1, aK);
      aQ = MFMA16(a2, bq2, aQ);  aK = MFMA16(bk2, a2, aK);
      aQ = MFMA16(a3f, bq3, aQ); aK = MFMA16(bk3, a3f, aK);
#pragma unroll
      for (int r = 0; r < 4; ++r)
        qa += fmaxf(aQ[r] + qb, 0.f);
      kacc[nt] = aK;
    }
    // reduce qsum over lg groups: all lanes hold qsum[dbase+dtl*16+lc]
    qa += __shfl_xor(qa, 16, 64);
    qa += __shfl_xor(qa, 32, 64);
    // redistribute: qv[r] = qsum at d = dbase+dtl*16+lg*4+r (from lane lg*4+r)
    const float qv0 = __shfl(qa, lg * 4 + 0, 64);
    const float qv1 = __shfl(qa, lg * 4 + 1, 64);
    const float qv2 = __shfl(qa, lg * 4 + 2, 64);
    const float qv3 = __shfl(qa, lg * 4 + 3, 64);

    // score partials: in-lane over r, then 2 shfls over lg
#pragma unroll
    for (int nt = 0; nt < 4; ++nt) {
      float pr = qv0 * fmaxf(kacc[nt][0] + kb4.x, 0.f);
      pr = fmaf(qv1, fmaxf(kacc[nt][1] + kb4.y, 0.f), pr);
      pr = fmaf(qv2, fmaxf(kacc[nt][2] + kb4.z, 0.f), pr);
      pr = fmaf(qv3, fmaxf(kacc[nt][3] + kb4.w, 0.f), pr);
      pr += __shfl_xor(pr, 16, 64);
      pr += __shfl_xor(pr, 32, 64);
      if (lg == 0) spart[dtl][wave][nt * 16 + lc] = pr;
    }
  }
  __syncthreads();  // spart ready (t_lds ready since previous barrier)

  // ---- phase D: softmax + output (wave 0 only) ----
  if (wave == 0) {
    const int m = lane;
    float sc = spart[0][0][m] + spart[0][1][m] + spart[0][2][m] + spart[0][3][m]
             + spart[1][0][m] + spart[1][1][m] + spart[1][2][m] + spart[1][3][m];
    sc = fmaxf(sc * kTemp, 0.f);
    float mx = sc;
#pragma unroll
    for (int off = 32; off > 0; off >>= 1) mx = fmaxf(mx, __shfl_xor(mx, off, 64));
    float e = __expf(sc - mx);
    float s = e;
#pragma unroll
    for (int off = 32; off > 0; off >>= 1) s += __shfl_xor(s, off, 64);
    float val = (e / s) * t_lds[m];
#pragma unroll
    for (int off = 32; off > 0; off >>= 1) val += __shfl_xor(val, off, 64);
    if (lane == 0) {
      float v = val + fws[134];
      const float* s0 = state + (size_t)b * (kN * kF);
#pragma unroll
      for (int j = 0; j < kSelf; ++j) v = fmaf(fws[128 + j], s0[j], v);
      out[b] = v;
    }
  }
}

extern "C" void kernel_launch(void* const* d_in, const int* in_sizes, int n_in,
                              void* d_out, int out_size, void* d_ws, size_t ws_size,
                              hipStream_t stream) {
  const float* state   = (const float*)d_in[0];
  const float* phi1_w  = (const float*)d_in[1];
  const float* phi1_b  = (const float*)d_in[2];
  const float* phi2_w  = (const float*)d_in[3];
  const float* phi2_b  = (const float*)d_in[4];
  const float* phi3_w  = (const float*)d_in[5];
  const float* phi3_b  = (const float*)d_in[6];
  const float* q_w     = (const float*)d_in[7];
  const float* q_b     = (const float*)d_in[8];
  const float* k_w     = (const float*)d_in[9];
  const float* k_b     = (const float*)d_in[10];
  const float* v_w     = (const float*)d_in[11];
  const float* v_b     = (const float*)d_in[12];
  const float* final_w = (const float*)d_in[13];
  const float* final_b = (const float*)d_in[14];
  float* out = (float*)d_out;
  ushort* ws = (ushort*)d_ws;

  prep_kernel<<<dim3(161), dim3(256), 0, stream>>>(
      q_w, k_w, phi3_w, phi2_w, phi3_b, phi2_b,
      v_w, phi1_w, phi1_b, v_b, final_w, final_b, ws);

  const int batches = in_sizes[0] / (kN * kF);  // 4096
  value_net_kernel<<<dim3(batches), dim3(256), 0, stream>>>(
      state, q_b, k_b, ws, out);
}